// Round 17
// baseline (30.949 us; speedup 1.0000x reference)
//
#include <hip/hip_runtime.h>
#include <hip/hip_bf16.h>
#include <math.h>

#define N_VOX 4096
#define LOG2E 1.44269504f

typedef __bf16 bf16x4 __attribute__((ext_vector_type(4)));
typedef __bf16 bf16x8 __attribute__((ext_vector_type(8)));
typedef float f32x4 __attribute__((ext_vector_type(4)));
typedef float f32x16 __attribute__((ext_vector_type(16)));

// ws layout (BYTES):
//   qt bf16[2][4096][16] @ 0        (PRE-SCALED by log2e)
//   kt bf16[2][4096][16] @ 262144
//   vp fp8 packed        @ 524288   1 MB
//     byte: ((b*256 + (j>>4))*2 + (c>>6))*1024
//           + ((((j>>3)&1)<<5) | (c&31))*16 + ((c>>5)&1)*8 + (j&7)
#define QT_OFF 0
#define KT_OFF 262144
#define VP_OFF 524288

__device__ __forceinline__ f32x16 mfma32_bf16(bf16x8 a, bf16x8 b, f32x16 c) {
  return __builtin_amdgcn_mfma_f32_32x32x16_bf16(a, b, c, 0, 0, 0);
}
__device__ __forceinline__ f32x16 mfma32_fp8(long a, long b, f32x16 c) {
  return __builtin_amdgcn_mfma_f32_32x32x16_fp8_fp8(a, b, c, 0, 0, 0);
}
__device__ __forceinline__ void pinl(long& v) { asm volatile("" : "+v"(v)); }
__device__ __forceinline__ void pinb(bf16x8& v) { asm volatile("" : "+v"(v)); }

__device__ __forceinline__ unsigned f32_to_fp8x4(float a, float b, float c, float d) {
  int v = __builtin_amdgcn_cvt_pk_fp8_f32(a, b, 0, false);
  v = __builtin_amdgcn_cvt_pk_fp8_f32(c, d, v, true);
  return (unsigned)v;
}
__device__ __forceinline__ unsigned char f32_to_fp8(float a) {
  return (unsigned char)(__builtin_amdgcn_cvt_pk_fp8_f32(a, a, 0, false) & 0xff);
}

// ---------------------------------------------------------------------------
// Kernel 1: q/k/v projections as MFMA GEMM (w staged bf16 in LDS).
// grid = 2 x 128 n-tiles of 32, 512 threads (8 waves). (r13-proven)
// ---------------------------------------------------------------------------
__global__ __launch_bounds__(512) void proj_kernel(
    const float* __restrict__ x,
    const float* __restrict__ wq, const float* __restrict__ bq,
    const float* __restrict__ wk, const float* __restrict__ bk,
    const float* __restrict__ wv, const float* __restrict__ bv,
    unsigned char* __restrict__ ws8) {
  __shared__ __bf16 xs[32 * 136];    // [n][c] pad 136            8.7 KB
  __shared__ __bf16 wb[160 * 136];   // q 0-15, k 16-31, v 32-159 43.5 KB

  const int t   = threadIdx.x;
  const int bid = blockIdx.x;        // 256 = 2 * 128
  const int b   = bid >> 7;
  const int n0  = (bid & 127) * 32;

  for (int i = t; i < 5120; i += 512) {
    int gid = i * 4;
    const float* src = (gid < 2048) ? wq + gid
                     : (gid < 4096) ? wk + (gid - 2048)
                                    : wv + (gid - 4096);
    float4 f = *reinterpret_cast<const float4*>(src);
    int r = gid >> 7, col = gid & 127;
    bf16x4 o;
    o[0] = (__bf16)f.x; o[1] = (__bf16)f.y; o[2] = (__bf16)f.z; o[3] = (__bf16)f.w;
    *reinterpret_cast<bf16x4*>(&wb[r * 136 + col]) = o;
  }
  for (int idx = t; idx < 128 * 8; idx += 512) {
    int c = idx >> 3, v4 = idx & 7;
    float4 xv = *reinterpret_cast<const float4*>(
        x + (size_t)(b * 128 + c) * N_VOX + n0 + v4 * 4);
    xs[(v4 * 4 + 0) * 136 + c] = (__bf16)xv.x;
    xs[(v4 * 4 + 1) * 136 + c] = (__bf16)xv.y;
    xs[(v4 * 4 + 2) * 136 + c] = (__bf16)xv.z;
    xs[(v4 * 4 + 3) * 136 + c] = (__bf16)xv.w;
  }
  __syncthreads();

  const int w = t >> 6, lane = t & 63;
  const int cq = lane & 15, g = lane >> 4, g8 = g * 8, g4 = g * 4;

  __bf16* qt = reinterpret_cast<__bf16*>(ws8 + QT_OFF);
  __bf16* kt = reinterpret_cast<__bf16*>(ws8 + KT_OFF);
  unsigned char* vp = ws8 + VP_OFF;
  const f32x4 zero4 = {0.f, 0.f, 0.f, 0.f};

  for (int ot = w; ot < 10; ot += 8) {
    int wrow = (ot == 0) ? cq : (ot == 1) ? 16 + cq : 32 + (ot - 2) * 16 + cq;
    const float* bias = (ot == 0) ? bq : (ot == 1) ? bk : bv + (ot - 2) * 16;

    f32x4 acc[2] = {zero4, zero4};
#pragma unroll
    for (int ks = 0; ks < 4; ++ks) {
      bf16x8 af = *reinterpret_cast<const bf16x8*>(&wb[wrow * 136 + ks * 32 + g8]);
#pragma unroll
      for (int nf = 0; nf < 2; ++nf) {
        bf16x8 bfr = *reinterpret_cast<const bf16x8*>(
            &xs[(nf * 16 + cq) * 136 + ks * 32 + g8]);
        acc[nf] = __builtin_amdgcn_mfma_f32_16x16x32_bf16(af, bfr, acc[nf], 0, 0, 0);
      }
    }

    float4 bl = *reinterpret_cast<const float4*>(bias + g4);
    const float* blp = reinterpret_cast<const float*>(&bl);
#pragma unroll
    for (int nf = 0; nf < 2; ++nf) {
      int n = n0 + nf * 16 + cq;
      if (ot < 2) {
        bf16x4 pk;
#pragma unroll
        for (int v = 0; v < 4; ++v) {
          float val = acc[nf][v] + blp[v];
          pk[v] = (__bf16)((ot == 0) ? val * LOG2E : val);
        }
        __bf16* dst = (ot == 0) ? qt : kt;
        *reinterpret_cast<bf16x4*>(dst + (size_t)(b * 4096 + n) * 16 + g4) = pk;
      } else {
#pragma unroll
        for (int v = 0; v < 4; ++v) {
          float val = acc[nf][v] + blp[v];
          int c = (ot - 2) * 16 + g4 + v;
          vp[(((size_t)(b * 256 + (n >> 4)) * 2 + (c >> 6)) << 10)
             + (((((n >> 3) & 1) << 5) | (c & 31)) * 16)
             + ((c >> 5) & 1) * 8 + (n & 7)] = f32_to_fp8(val);
        }
      }
    }
  }
}

// ---------------------------------------------------------------------------
// attn tile body: consumes V from VCUR (loaded last tile), prefetches
// V(T+1) into VNXT and K(T+1) into kn. Static buffers -> no scratch.
// ---------------------------------------------------------------------------
#define ATTN_TILE(T, VCUR, VNXT)                                               \
  {                                                                            \
    const int jtn = jt_base + (((T) + 1) & 7);                                 \
    /* prefetch next tile's V and K */                                         \
    _Pragma("unroll")                                                          \
    for (int jc = 0; jc < 4; ++jc)                                             \
      _Pragma("unroll")                                                        \
      for (int ch = 0; ch < 2; ++ch) {                                         \
        long2 L = *reinterpret_cast<const long2*>(                             \
            vbase + (((size_t)(jtn * 4 + jc) * 2 + ch) << 10));                \
        VNXT[jc][2 * ch] = L.x; VNXT[jc][2 * ch + 1] = L.y;                    \
      }                                                                        \
    bf16x8 kn0 = *reinterpret_cast<const bf16x8*>(kbase + (size_t)(jtn * 64) * 16);        \
    bf16x8 kn1 = *reinterpret_cast<const bf16x8*>(kbase + (size_t)(jtn * 64 + 32) * 16);   \
    /* QK^T (K prefetched last tile) */                                        \
    f32x16 sf0 = mfma32_bf16(kf0, qf, zero16);                                 \
    f32x16 sf1 = mfma32_bf16(kf1, qf, zero16);                                 \
    /* tmax: depth-5 tree + shfl cross-half */                                 \
    float mx[8];                                                               \
    _Pragma("unroll")                                                          \
    for (int i = 0; i < 8; ++i)                                                \
      mx[i] = fmaxf(fmaxf(sf0[2 * i], sf0[2 * i + 1]),                         \
                    fmaxf(sf1[2 * i], sf1[2 * i + 1]));                        \
    float m01 = fmaxf(mx[0], mx[1]), m23 = fmaxf(mx[2], mx[3]);                \
    float m45 = fmaxf(mx[4], mx[5]), m67 = fmaxf(mx[6], mx[7]);                \
    float tmax = fmaxf(fmaxf(m01, m23), fmaxf(m45, m67));                      \
    tmax = fmaxf(tmax, __shfl_xor(tmax, 32));                                  \
    if (__any(tmax > m + 8.0f)) {                                              \
      float mn = fmaxf(m, tmax);                                               \
      float sc = exp2f(m - mn);                                                \
      _Pragma("unroll")                                                        \
      for (int cb = 0; cb < 4; ++cb)                                           \
        _Pragma("unroll")                                                      \
        for (int r = 0; r < 16; ++r) acc[cb][r] *= sc;                         \
      l *= sc;                                                                 \
      m = mn;                                                                  \
    }                                                                          \
    float ps[8];                                                               \
    unsigned W0[4], W1[4], X0[4], X1[4];                                       \
    _Pragma("unroll")                                                          \
    for (int i = 0; i < 4; ++i) {                                              \
      float a = exp2f(sf0[4 * i] - m),     bb = exp2f(sf0[4 * i + 1] - m);     \
      float c = exp2f(sf0[4 * i + 2] - m), d  = exp2f(sf0[4 * i + 3] - m);     \
      ps[i] = (a + bb) + (c + d);                                              \
      W0[i] = f32_to_fp8x4(a, bb, c, d);                                       \
    }                                                                          \
    _Pragma("unroll")                                                          \
    for (int i = 0; i < 4; ++i) {                                              \
      float a = exp2f(sf1[4 * i] - m),     bb = exp2f(sf1[4 * i + 1] - m);     \
      float c = exp2f(sf1[4 * i + 2] - m), d  = exp2f(sf1[4 * i + 3] - m);     \
      ps[4 + i] = (a + bb) + (c + d);                                          \
      W1[i] = f32_to_fp8x4(a, bb, c, d);                                       \
    }                                                                          \
    float psum = ((ps[0] + ps[1]) + (ps[2] + ps[3])) +                         \
                 ((ps[4] + ps[5]) + (ps[6] + ps[7]));                          \
    l += psum + __shfl_xor(psum, 32);                                          \
    _Pragma("unroll")                                                          \
    for (int i = 0; i < 4; ++i) {                                              \
      X0[i] = __shfl_xor(W0[i], 32);                                           \
      X1[i] = __shfl_xor(W1[i], 32);                                           \
    }                                                                          \
    _Pragma("unroll")                                                          \
    for (int jc = 0; jc < 4; ++jc)                                             \
      _Pragma("unroll")                                                        \
      for (int cb = 0; cb < 4; ++cb) pinl(VCUR[jc][cb]);                       \
    pinb(kn0); pinb(kn1);                                                      \
    __builtin_amdgcn_s_setprio(1);                                             \
    _Pragma("unroll")                                                          \
    for (int jc = 0; jc < 4; ++jc) {                                           \
      const int pb = (jc & 1) * 2;                                             \
      unsigned wd0, wd1;                                                       \
      if (jc < 2) {                                                            \
        wd0 = hi ? X0[pb + 1] : W0[pb];                                        \
        wd1 = hi ? W0[pb + 1] : X0[pb];                                        \
      } else {                                                                 \
        wd0 = hi ? X1[pb + 1] : W1[pb];                                        \
        wd1 = hi ? W1[pb + 1] : X1[pb];                                        \
      }                                                                        \
      long pf = (long)(((unsigned long long)wd1 << 32) | wd0);                 \
      _Pragma("unroll")                                                        \
      for (int cb = 0; cb < 4; ++cb)                                           \
        acc[cb] = mfma32_fp8(VCUR[jc][cb], pf, acc[cb]);                       \
    }                                                                          \
    __builtin_amdgcn_s_setprio(0);                                             \
    kf0 = kn0; kf1 = kn1;                                                      \
  }

// ---------------------------------------------------------------------------
// Kernel 2: fused flash attention, 32x32x16 path, log2 softmax.
// This round: V double-buffered in registers (1 tile in flight, like K) —
// ping-pong buffers vfA/vfB via hand-expanded 2-body loop (static indices).
// ---------------------------------------------------------------------------
__global__ __launch_bounds__(512, 2) void attn_kernel(
    const unsigned char* __restrict__ ws8,
    const float* __restrict__ x,
    const float* __restrict__ gamma_p,
    float* __restrict__ out) {
  __shared__ float o_lds[4][128][33];                 // 67.6 KB
  __shared__ float m_lds[8][32], l_lds[8][32], lstar_lds[32];

  const int t    = threadIdx.x;
  const int w    = t >> 6;
  const int lane = t & 63;
  const int l31  = lane & 31;
  const int hi   = lane >> 5;

  const int raw = blockIdx.x;            // 256
  const int xcd = raw & 7;
  const int b   = xcd >> 2;
  const int qt0 = ((raw >> 3) * 4 + (xcd & 3)) * 32;

  const __bf16* qt = reinterpret_cast<const __bf16*>(ws8 + QT_OFF);
  const __bf16* kt = reinterpret_cast<const __bf16*>(ws8 + KT_OFF);
  const unsigned char* vp = ws8 + VP_OFF;

  bf16x8 qf = *reinterpret_cast<const bf16x8*>(
      qt + (size_t)(b * 4096 + qt0 + l31) * 16 + hi * 8);

  f32x16 acc[4];
#pragma unroll
  for (int cb = 0; cb < 4; ++cb)
#pragma unroll
    for (int r = 0; r < 16; ++r) acc[cb][r] = 0.f;
  const f32x16 zero16 = acc[0];
  float m = -1e30f, l = 0.f;

  const __bf16* kbase = kt + (size_t)(b * 4096 + l31) * 16 + hi * 8;
  const unsigned char* vbase = vp + (size_t)b * 524288 + lane * 16;

  const int jt_base = w * 8;

  // prologue: K(0) and V(0) in flight
  bf16x8 kf0 = *reinterpret_cast<const bf16x8*>(kbase + (size_t)(jt_base * 64) * 16);
  bf16x8 kf1 = *reinterpret_cast<const bf16x8*>(kbase + (size_t)(jt_base * 64 + 32) * 16);
  long vfA[4][4], vfB[4][4];
#pragma unroll
  for (int jc = 0; jc < 4; ++jc)
#pragma unroll
    for (int ch = 0; ch < 2; ++ch) {
      long2 L = *reinterpret_cast<const long2*>(
          vbase + (((size_t)(jt_base * 4 + jc) * 2 + ch) << 10));
      vfA[jc][2 * ch] = L.x; vfA[jc][2 * ch + 1] = L.y;
    }

#pragma unroll 1
  for (int tt = 0; tt < 4; ++tt) {
    ATTN_TILE(jt_base - jt_base + 2 * tt,     vfA, vfB)   // tile 2tt
    ATTN_TILE(2 * tt + 1,                     vfB, vfA)   // tile 2tt+1
  }

  // ---- cross-wave merge (8 partials, log2 domain) ----
  if (lane < 32) { m_lds[w][lane] = m; l_lds[w][lane] = l; }
  __syncthreads();

  float mstar = m_lds[0][l31];
#pragma unroll
  for (int ww = 1; ww < 8; ++ww) mstar = fmaxf(mstar, m_lds[ww][l31]);
  float lstar = 0.f;
#pragma unroll
  for (int ww = 0; ww < 8; ++ww)
    lstar += l_lds[ww][l31] * exp2f(m_lds[ww][l31] - mstar);
  float sc = exp2f(m - mstar);
  if (w == 0 && lane < 32) lstar_lds[lane] = lstar;

  const int rr = w & 3;
  if (w < 4) {
#pragma unroll
    for (int cb = 0; cb < 4; ++cb)
#pragma unroll
      for (int r = 0; r < 16; ++r)
        o_lds[rr][cb * 32 + (r & 3) + 8 * (r >> 2) + 4 * hi][l31] = acc[cb][r] * sc;
  }
  __syncthreads();
  if (w >= 4) {
#pragma unroll
    for (int cb = 0; cb < 4; ++cb)
#pragma unroll
      for (int r = 0; r < 16; ++r)
        o_lds[rr][cb * 32 + (r & 3) + 8 * (r >> 2) + 4 * hi][l31] += acc[cb][r] * sc;
  }
  __syncthreads();

  // ---- epilogue: out = gamma * O/l + x ----
  const float g0 = gamma_p[0];
  for (int idx = t; idx < 128 * 32; idx += 512) {
    int c = idx >> 5, qq = idx & 31;
    float o = (o_lds[0][c][qq] + o_lds[1][c][qq] +
               o_lds[2][c][qq] + o_lds[3][c][qq]) / lstar_lds[qq];
    size_t addr = (size_t)(b * 128 + c) * N_VOX + qt0 + qq;
    out[addr] = fmaf(g0, o, x[addr]);
  }
}

// ---------------------------------------------------------------------------
extern "C" void kernel_launch(void* const* d_in, const int* in_sizes, int n_in,
                              void* d_out, int out_size, void* d_ws, size_t ws_size,
                              hipStream_t stream) {
  const float* x     = (const float*)d_in[0];
  const float* wq    = (const float*)d_in[1];
  const float* bq    = (const float*)d_in[2];
  const float* wk    = (const float*)d_in[3];
  const float* bk    = (const float*)d_in[4];
  const float* wv    = (const float*)d_in[5];
  const float* bv    = (const float*)d_in[6];
  const float* gamma = (const float*)d_in[7];
  float* out = (float*)d_out;
  unsigned char* ws8 = (unsigned char*)d_ws;   // 1.5 MB

  proj_kernel<<<256, 512, 0, stream>>>(x, wq, bq, wk, bk, wv, bv, ws8);
  attn_kernel<<<256, 512, 0, stream>>>(ws8, x, gamma, out);
}

// Round 18
// 30.148 us; speedup vs baseline: 1.0266x; 1.0266x over previous
//
#include <hip/hip_runtime.h>
#include <hip/hip_bf16.h>
#include <math.h>

#define N_VOX 4096
#define LOG2E 1.44269504f

typedef __bf16 bf16x4 __attribute__((ext_vector_type(4)));
typedef __bf16 bf16x8 __attribute__((ext_vector_type(8)));
typedef float f32x4 __attribute__((ext_vector_type(4)));
typedef float f32x16 __attribute__((ext_vector_type(16)));

// ws layout (BYTES):
//   qt bf16[2][4096][16] @ 0        (PRE-SCALED by log2e)
//   kt bf16[2][4096][16] @ 262144
//   vp fp8 packed        @ 524288   1 MB
//     byte: ((b*256 + (j>>4))*2 + (c>>6))*1024
//           + ((((j>>3)&1)<<5) | (c&31))*16 + ((c>>5)&1)*8 + (j&7)
#define QT_OFF 0
#define KT_OFF 262144
#define VP_OFF 524288

__device__ __forceinline__ f32x16 mfma32_bf16(bf16x8 a, bf16x8 b, f32x16 c) {
  return __builtin_amdgcn_mfma_f32_32x32x16_bf16(a, b, c, 0, 0, 0);
}
__device__ __forceinline__ f32x16 mfma32_fp8(long a, long b, f32x16 c) {
  return __builtin_amdgcn_mfma_f32_32x32x16_fp8_fp8(a, b, c, 0, 0, 0);
}
__device__ __forceinline__ void pinl(long& v) { asm volatile("" : "+v"(v)); }
__device__ __forceinline__ void pinb(bf16x8& v) { asm volatile("" : "+v"(v)); }

__device__ __forceinline__ unsigned f32_to_fp8x4(float a, float b, float c, float d) {
  int v = __builtin_amdgcn_cvt_pk_fp8_f32(a, b, 0, false);
  v = __builtin_amdgcn_cvt_pk_fp8_f32(c, d, v, true);
  return (unsigned)v;
}
__device__ __forceinline__ unsigned char f32_to_fp8(float a) {
  return (unsigned char)(__builtin_amdgcn_cvt_pk_fp8_f32(a, a, 0, false) & 0xff);
}

// ---------------------------------------------------------------------------
// Kernel 1: q/k/v projections as MFMA GEMM (w staged bf16 in LDS).
// grid = 2 x 128 n-tiles of 32, 512 threads (8 waves).
// ---------------------------------------------------------------------------
__global__ __launch_bounds__(512) void proj_kernel(
    const float* __restrict__ x,
    const float* __restrict__ wq, const float* __restrict__ bq,
    const float* __restrict__ wk, const float* __restrict__ bk,
    const float* __restrict__ wv, const float* __restrict__ bv,
    unsigned char* __restrict__ ws8) {
  __shared__ __bf16 xs[32 * 136];    // [n][c] pad 136            8.7 KB
  __shared__ __bf16 wb[160 * 136];   // q 0-15, k 16-31, v 32-159 43.5 KB

  const int t   = threadIdx.x;
  const int bid = blockIdx.x;        // 256 = 2 * 128
  const int b   = bid >> 7;
  const int n0  = (bid & 127) * 32;

  for (int i = t; i < 5120; i += 512) {
    int gid = i * 4;
    const float* src = (gid < 2048) ? wq + gid
                     : (gid < 4096) ? wk + (gid - 2048)
                                    : wv + (gid - 4096);
    float4 f = *reinterpret_cast<const float4*>(src);
    int r = gid >> 7, col = gid & 127;
    bf16x4 o;
    o[0] = (__bf16)f.x; o[1] = (__bf16)f.y; o[2] = (__bf16)f.z; o[3] = (__bf16)f.w;
    *reinterpret_cast<bf16x4*>(&wb[r * 136 + col]) = o;
  }
  for (int idx = t; idx < 128 * 8; idx += 512) {
    int c = idx >> 3, v4 = idx & 7;
    float4 xv = *reinterpret_cast<const float4*>(
        x + (size_t)(b * 128 + c) * N_VOX + n0 + v4 * 4);
    xs[(v4 * 4 + 0) * 136 + c] = (__bf16)xv.x;
    xs[(v4 * 4 + 1) * 136 + c] = (__bf16)xv.y;
    xs[(v4 * 4 + 2) * 136 + c] = (__bf16)xv.z;
    xs[(v4 * 4 + 3) * 136 + c] = (__bf16)xv.w;
  }
  __syncthreads();

  const int w = t >> 6, lane = t & 63;
  const int cq = lane & 15, g = lane >> 4, g8 = g * 8, g4 = g * 4;

  __bf16* qt = reinterpret_cast<__bf16*>(ws8 + QT_OFF);
  __bf16* kt = reinterpret_cast<__bf16*>(ws8 + KT_OFF);
  unsigned char* vp = ws8 + VP_OFF;
  const f32x4 zero4 = {0.f, 0.f, 0.f, 0.f};

  for (int ot = w; ot < 10; ot += 8) {
    int wrow = (ot == 0) ? cq : (ot == 1) ? 16 + cq : 32 + (ot - 2) * 16 + cq;
    const float* bias = (ot == 0) ? bq : (ot == 1) ? bk : bv + (ot - 2) * 16;

    f32x4 acc[2] = {zero4, zero4};
#pragma unroll
    for (int ks = 0; ks < 4; ++ks) {
      bf16x8 af = *reinterpret_cast<const bf16x8*>(&wb[wrow * 136 + ks * 32 + g8]);
#pragma unroll
      for (int nf = 0; nf < 2; ++nf) {
        bf16x8 bfr = *reinterpret_cast<const bf16x8*>(
            &xs[(nf * 16 + cq) * 136 + ks * 32 + g8]);
        acc[nf] = __builtin_amdgcn_mfma_f32_16x16x32_bf16(af, bfr, acc[nf], 0, 0, 0);
      }
    }

    float4 bl = *reinterpret_cast<const float4*>(bias + g4);
    const float* blp = reinterpret_cast<const float*>(&bl);
#pragma unroll
    for (int nf = 0; nf < 2; ++nf) {
      int n = n0 + nf * 16 + cq;
      if (ot < 2) {
        bf16x4 pk;
#pragma unroll
        for (int v = 0; v < 4; ++v) {
          float val = acc[nf][v] + blp[v];
          pk[v] = (__bf16)((ot == 0) ? val * LOG2E : val);
        }
        __bf16* dst = (ot == 0) ? qt : kt;
        *reinterpret_cast<bf16x4*>(dst + (size_t)(b * 4096 + n) * 16 + g4) = pk;
      } else {
#pragma unroll
        for (int v = 0; v < 4; ++v) {
          float val = acc[nf][v] + blp[v];
          int c = (ot - 2) * 16 + g4 + v;
          vp[(((size_t)(b * 256 + (n >> 4)) * 2 + (c >> 6)) << 10)
             + (((((n >> 3) & 1) << 5) | (c & 31)) * 16)
             + ((c >> 5) & 1) * 8 + (n & 7)] = f32_to_fp8(val);
        }
      }
    }
  }
}

// ---------------------------------------------------------------------------
// Kernel 2: fused flash attention, 32x32x16 MFMA path, log2-domain softmax.
// grid = 256 (b x 128 q-tiles of 32), 512 thr = 8 waves, wave: 32q x 512 keys.
// p = exp2(s - m) <= 2^8 = 256 < 448 (defer-max THR=8, log2 units).
// P in-register via fused exp2+cvt_pk + shfl_xor(32). V loads 8 x 16B.
// (best-measured configuration: 30.23 us, absmax 0.015625)
// ---------------------------------------------------------------------------
__global__ __launch_bounds__(512, 2) void attn_kernel(
    const unsigned char* __restrict__ ws8,
    const float* __restrict__ x,
    const float* __restrict__ gamma_p,
    float* __restrict__ out) {
  __shared__ float o_lds[4][128][33];                 // 67.6 KB
  __shared__ float m_lds[8][32], l_lds[8][32], lstar_lds[32];

  const int t    = threadIdx.x;
  const int w    = t >> 6;
  const int lane = t & 63;
  const int l31  = lane & 31;
  const int hi   = lane >> 5;

  const int raw = blockIdx.x;            // 256
  const int xcd = raw & 7;
  const int b   = xcd >> 2;
  const int qt0 = ((raw >> 3) * 4 + (xcd & 3)) * 32;

  const __bf16* qt = reinterpret_cast<const __bf16*>(ws8 + QT_OFF);
  const __bf16* kt = reinterpret_cast<const __bf16*>(ws8 + KT_OFF);
  const unsigned char* vp = ws8 + VP_OFF;

  bf16x8 qf = *reinterpret_cast<const bf16x8*>(
      qt + (size_t)(b * 4096 + qt0 + l31) * 16 + hi * 8);

  f32x16 acc[4];
#pragma unroll
  for (int cb = 0; cb < 4; ++cb)
#pragma unroll
    for (int r = 0; r < 16; ++r) acc[cb][r] = 0.f;
  const f32x16 zero16 = acc[0];
  float m = -1e30f, l = 0.f;

  const __bf16* kbase = kt + (size_t)(b * 4096 + l31) * 16 + hi * 8;
  const unsigned char* vbase = vp + (size_t)b * 524288 + lane * 16;

  const int jt_base = w * 8;

  bf16x8 kf0 = *reinterpret_cast<const bf16x8*>(kbase + (size_t)(jt_base * 64) * 16);
  bf16x8 kf1 = *reinterpret_cast<const bf16x8*>(kbase + (size_t)(jt_base * 64 + 32) * 16);

#pragma unroll 1
  for (int tile = 0; tile < 8; ++tile) {
    const int jt = jt_base + tile;
    const int jtn = jt_base + ((tile + 1) & 7);

    // ---- issue 8 V loads (16B each) + 2 next-K loads ----
    long vf[4][4];
#pragma unroll
    for (int jc = 0; jc < 4; ++jc)
#pragma unroll
      for (int ch = 0; ch < 2; ++ch) {
        long2 L = *reinterpret_cast<const long2*>(
            vbase + (((size_t)(jt * 4 + jc) * 2 + ch) << 10));
        vf[jc][2 * ch] = L.x; vf[jc][2 * ch + 1] = L.y;
      }
    bf16x8 kn0 = *reinterpret_cast<const bf16x8*>(kbase + (size_t)(jtn * 64) * 16);
    bf16x8 kn1 = *reinterpret_cast<const bf16x8*>(kbase + (size_t)(jtn * 64 + 32) * 16);

    // ---- QK^T: sf[r] = S^T[j][q], j = (r&3)+8*(r>>2)+4*hi (+32 for sf1) ----
    f32x16 sf0 = mfma32_bf16(kf0, qf, zero16);
    f32x16 sf1 = mfma32_bf16(kf1, qf, zero16);

    // ---- online softmax (log2 domain): lane owns q = l31, 32 j-values ----
    float tmax = sf0[0];
#pragma unroll
    for (int r = 1; r < 16; ++r) tmax = fmaxf(tmax, sf0[r]);
#pragma unroll
    for (int r = 0; r < 16; ++r) tmax = fmaxf(tmax, sf1[r]);
    tmax = fmaxf(tmax, __shfl_xor(tmax, 32));

    if (__any(tmax > m + 8.0f)) {                    // defer-max
      float mn = fmaxf(m, tmax);
      float sc = exp2f(m - mn);
#pragma unroll
      for (int cb = 0; cb < 4; ++cb)
#pragma unroll
        for (int r = 0; r < 16; ++r) acc[cb][r] *= sc;
      l *= sc;
      m = mn;
    }

    // fused exp2 -> psum -> fp8 pack (4 live floats at a time)
    float psum = 0.f;
    unsigned W0[4], W1[4], X0[4], X1[4];
#pragma unroll
    for (int i = 0; i < 4; ++i) {
      float a = exp2f(sf0[4 * i] - m),     bb = exp2f(sf0[4 * i + 1] - m);
      float c = exp2f(sf0[4 * i + 2] - m), d  = exp2f(sf0[4 * i + 3] - m);
      psum += (a + bb) + (c + d);
      W0[i] = f32_to_fp8x4(a, bb, c, d);
    }
#pragma unroll
    for (int i = 0; i < 4; ++i) {
      float a = exp2f(sf1[4 * i] - m),     bb = exp2f(sf1[4 * i + 1] - m);
      float c = exp2f(sf1[4 * i + 2] - m), d  = exp2f(sf1[4 * i + 3] - m);
      psum += (a + bb) + (c + d);
      W1[i] = f32_to_fp8x4(a, bb, c, d);
    }
    psum += __shfl_xor(psum, 32);
    l += psum;

#pragma unroll
    for (int i = 0; i < 4; ++i) {
      X0[i] = __shfl_xor(W0[i], 32);
      X1[i] = __shfl_xor(W1[i], 32);
    }

    // ---- PV: per j16-chunk jc, B-frag = (word0 = e0..3, word1 = e4..7) ----
#pragma unroll
    for (int jc = 0; jc < 4; ++jc)
#pragma unroll
      for (int cb = 0; cb < 4; ++cb) pinl(vf[jc][cb]);
    pinb(kn0); pinb(kn1);

    __builtin_amdgcn_s_setprio(1);
#pragma unroll
    for (int jc = 0; jc < 4; ++jc) {
      const int pb = (jc & 1) * 2;
      unsigned wd0, wd1;
      if (jc < 2) {
        wd0 = hi ? X0[pb + 1] : W0[pb];
        wd1 = hi ? W0[pb + 1] : X0[pb];
      } else {
        wd0 = hi ? X1[pb + 1] : W1[pb];
        wd1 = hi ? W1[pb + 1] : X1[pb];
      }
      long pf = (long)(((unsigned long long)wd1 << 32) | wd0);
#pragma unroll
      for (int cb = 0; cb < 4; ++cb)
        acc[cb] = mfma32_fp8(vf[jc][cb], pf, acc[cb]);
    }
    __builtin_amdgcn_s_setprio(0);

    kf0 = kn0; kf1 = kn1;
  }

  // ---- cross-wave merge (8 partials, log2 domain) ----
  if (lane < 32) { m_lds[w][lane] = m; l_lds[w][lane] = l; }
  __syncthreads();

  float mstar = m_lds[0][l31];
#pragma unroll
  for (int ww = 1; ww < 8; ++ww) mstar = fmaxf(mstar, m_lds[ww][l31]);
  float lstar = 0.f;
#pragma unroll
  for (int ww = 0; ww < 8; ++ww)
    lstar += l_lds[ww][l31] * exp2f(m_lds[ww][l31] - mstar);
  float sc = exp2f(m - mstar);
  if (w == 0 && lane < 32) lstar_lds[lane] = lstar;

  const int rr = w & 3;
  if (w < 4) {
#pragma unroll
    for (int cb = 0; cb < 4; ++cb)
#pragma unroll
      for (int r = 0; r < 16; ++r)
        o_lds[rr][cb * 32 + (r & 3) + 8 * (r >> 2) + 4 * hi][l31] = acc[cb][r] * sc;
  }
  __syncthreads();
  if (w >= 4) {
#pragma unroll
    for (int cb = 0; cb < 4; ++cb)
#pragma unroll
      for (int r = 0; r < 16; ++r)
        o_lds[rr][cb * 32 + (r & 3) + 8 * (r >> 2) + 4 * hi][l31] += acc[cb][r] * sc;
  }
  __syncthreads();

  // ---- epilogue: out = gamma * O/l + x ----
  const float g0 = gamma_p[0];
  for (int idx = t; idx < 128 * 32; idx += 512) {
    int c = idx >> 5, qq = idx & 31;
    float o = (o_lds[0][c][qq] + o_lds[1][c][qq] +
               o_lds[2][c][qq] + o_lds[3][c][qq]) / lstar_lds[qq];
    size_t addr = (size_t)(b * 128 + c) * N_VOX + qt0 + qq;
    out[addr] = fmaf(g0, o, x[addr]);
  }
}

// ---------------------------------------------------------------------------
extern "C" void kernel_launch(void* const* d_in, const int* in_sizes, int n_in,
                              void* d_out, int out_size, void* d_ws, size_t ws_size,
                              hipStream_t stream) {
  const float* x     = (const float*)d_in[0];
  const float* wq    = (const float*)d_in[1];
  const float* bq    = (const float*)d_in[2];
  const float* wk    = (const float*)d_in[3];
  const float* bk    = (const float*)d_in[4];
  const float* wv    = (const float*)d_in[5];
  const float* bv    = (const float*)d_in[6];
  const float* gamma = (const float*)d_in[7];
  float* out = (float*)d_out;
  unsigned char* ws8 = (unsigned char*)d_ws;   // 1.5 MB

  proj_kernel<<<256, 512, 0, stream>>>(x, wq, bq, wk, bk, wv, bv, ws8);
  attn_kernel<<<256, 512, 0, stream>>>(ws8, x, gamma, out);
}